// Round 6
// baseline (744.994 us; speedup 1.0000x reference)
//
#include <hip/hip_runtime.h>
#include <math.h>

#define BB 8
#define LL 4096
#define DD 512
#define PTOT (BB*LL)      // 32768 positions
#define HID  2048

typedef __attribute__((ext_vector_type(8))) short short8;   // 8 bf16 (4 VGPRs)
typedef __attribute__((ext_vector_type(4))) float f32x4;

typedef __attribute__((address_space(1))) const unsigned int gconst_u32;
typedef __attribute__((address_space(3))) unsigned int lds_u32;

__device__ __forceinline__ void gload16(const void* g, void* l) {
    // async global->LDS DMA, 16B per lane; LDS dest = wave-uniform base + lane*16
    __builtin_amdgcn_global_load_lds((gconst_u32*)g, (lds_u32*)l, 16, 0, 0);
}

__device__ __forceinline__ unsigned short f2bf(float f) {
    union { float f; unsigned int u; } v; v.f = f;
    unsigned int r = v.u + 0x7fffu + ((v.u >> 16) & 1u);
    return (unsigned short)(r >> 16);
}
__device__ __forceinline__ float bf2f(unsigned short h) {
    union { unsigned int u; float f; } v; v.u = ((unsigned int)h) << 16;
    return v.f;
}
__device__ __forceinline__ float gelu_fast(float x) {
    float x2 = x * x;
    float t  = x * fmaf(0.044715f, x2, 1.0f);
    float e  = __builtin_amdgcn_exp2f(-2.3021143f * t);   // e^{-2z}
    return x * __builtin_amdgcn_rcpf(1.0f + e);
}

__device__ __forceinline__ void barrier_sync() {
    asm volatile("" ::: "memory");
    __builtin_amdgcn_s_barrier();
    asm volatile("" ::: "memory");
}
#define WAITV(N) asm volatile("s_waitcnt vmcnt(" #N ")" ::: "memory")
#define WAITL0() asm volatile("s_waitcnt lgkmcnt(0)" ::: "memory")

// ---------------------------------------------------------------------------
// x fp32 -> bf16; also zero the 256B zero-page (ws is re-poisoned each launch)
__global__ __launch_bounds__(256) void convert_x(const float* __restrict__ x,
                                                 unsigned short* __restrict__ xb,
                                                 unsigned short* __restrict__ zp) {
    int tid = blockIdx.x * 256 + threadIdx.x;
    if (blockIdx.x == 0 && threadIdx.x < 128) zp[threadIdx.x] = 0;
    float4 v = ((const float4*)x)[tid];
    uint2 o;
    o.x = (unsigned int)f2bf(v.x) | ((unsigned int)f2bf(v.y) << 16);
    o.y = (unsigned int)f2bf(v.z) | ((unsigned int)f2bf(v.w) << 16);
    ((uint2*)xb)[tid] = o;
}

// conv W (o,c,k) -> Wt[o][k*512+c] bf16
__global__ __launch_bounds__(256) void trans_wconv(const float* __restrict__ W,
                                                   unsigned short* __restrict__ Wt, int K) {
    int tid = blockIdx.x * 256 + threadIdx.x;
    if (tid >= DD * DD * K) return;
    int o  = tid / (K * DD);
    int kc = tid - o * K * DD;
    int k  = kc >> 9;
    int c  = kc & (DD - 1);
    Wt[tid] = f2bf(W[(o * DD + c) * K + k]);
}

// mlp_w1 (c, n) -> W1t[n][c]
__global__ __launch_bounds__(256) void trans_w1(const float* __restrict__ W,
                                                unsigned short* __restrict__ Wt) {
    int tid = blockIdx.x * 256 + threadIdx.x;   // n*512 + c
    int n = tid >> 9;
    int c = tid & (DD - 1);
    Wt[tid] = f2bf(W[c * HID + n]);
}

// mlp_w2 (h, n) -> W2t[n][h]
__global__ __launch_bounds__(256) void trans_w2(const float* __restrict__ W,
                                                unsigned short* __restrict__ Wt) {
    int tid = blockIdx.x * 256 + threadIdx.x;   // n*2048 + h
    int n = tid >> 11;
    int h = tid & (HID - 1);
    Wt[tid] = f2bf(W[h * DD + n]);
}

// srcp[p*K + k] = p + k - pad if in-range and chain matches, else -1
__global__ __launch_bounds__(256) void make_srcp(const int* __restrict__ chain,
                                                 int* __restrict__ srcp, int K) {
    int tid = blockIdx.x * 256 + threadIdx.x;
    if (tid >= PTOT * K) return;
    int p = tid / K;
    int k = tid - p * K;
    int b = p >> 12;
    int l = p & (LL - 1);
    int pad = (K - 1) >> 1;
    int l2 = l + k - pad;
    bool ok = (l2 >= 0) && (l2 < LL) && (chain[b * LL + l2] == chain[b * LL + l]);
    srcp[tid] = ok ? (p + k - pad) : -1;
}

// ---------------------------------------------------------------------------
// 256x256 MFMA GEMM, unpinned-phase variant (round 6).
// 512 threads = 8 waves (2M x 4N), wave tile 128x64, BK=64, dbuf LDS 128KB.
// Per K-tile, 4 phases; per-wave phase = STG | RD | [compiler-scheduled MFMA
// with auto counted lgkmcnt] | lgkmcnt(0) | bar.
// vs round 5: NO WAITL0+sched_barrier(0) between RD and MFMA (m141: pinning
// regresses; m97: compiler's ds_read->MFMA lgkmcnt is near-optimal). The
// end-of-phase lgkmcnt(0) preserves the invariant "all of a wave's phase-N
// LDS reads retire before its phase-N barrier" (loads cannot cross the asm
// memory clobber), so the overwrite-safety derivation from round 5 holds:
//   A1: rd ph3(kt-1) -> DMA iss ph1(kt) = +2 barriers; B1: ph2->ph2 = +4;
//   A0: ph1->ph3 = +2; B0: ph1->ph4 = +3.
// STG issued FIRST in each phase (DMA to memory system earlier; aliasing
// keeps ds_reads after it, so per-phase vmem op order/count is unchanged and
// the counted-vmcnt arithmetic survives: WAITV(4) at end-ph4 => streams
// <=4kt+7 landed = all of tile kt+1's needs; WAITV(0) at end of tile NKT-2).
// ds_read counts 12/4/8/0 per phase (frag reuse):
//   ph1 (0,0): af<-A0 + bf0<-B0; ph2 (0,1): bf1<-B1; ph3 (1,0): af<-A1;
//   ph4 (1,1): none.
// EPI: 0 bf16=acc+bias; 1 bf16=gelu(acc+bias); 2 f32=acc+bias; 3 f32+=acc.
template <int TAPS, int EPI>
__global__ __launch_bounds__(512) void mfma_gemm5(
        const unsigned short* __restrict__ A, int lda,
        const int* __restrict__ srcp,
        const unsigned short* __restrict__ Bt, int ldb,
        const float* __restrict__ bias,
        void* __restrict__ Yv, int ldc, int Kspan,
        const unsigned short* __restrict__ zp) {
    __shared__ alignas(16) unsigned short As[2 * 256 * 64];   // 64 KB
    __shared__ alignas(16) unsigned short Bs[2 * 256 * 64];   // 64 KB
    __shared__ int srcp_s[TAPS > 0 ? 256 * TAPS : 4];         // <=7 KB

    const int t = threadIdx.x;
    const int lane = t & 63, w = t >> 6;
    const int wr = w & 1, wc = w >> 1;          // 2M x 4N waves
    const int lm = lane & 15, qh = lane >> 4, x7 = lane & 7;
    const int qq = (lane & 7) ^ (lane >> 3);    // staged source quad (swizzle)
    const int l3 = lane >> 3;                   // row-within-8
    const int p0 = blockIdx.x * 256;
    const int o0 = blockIdx.y * 256;
    const int NKT = TAPS ? TAPS * 8 : (Kspan >> 6);

    f32x4 acc[8][4];
#pragma unroll
    for (int mi = 0; mi < 8; mi++)
#pragma unroll
        for (int nj = 0; nj < 4; nj++) acc[mi][nj] = (f32x4){0.f, 0.f, 0.f, 0.f};

    // stream h: tile jt=h>>2 (buffer jt&1); h&1: 0=A,1=B; h&2: row half
    auto stgB = [&](int h) {
        if (h >= 4 * NKT) return;
        int jt = h >> 2;
        int rb = (h & 2) ? 128 : 0;
        unsigned short* dst = Bs + (jt & 1) * 16384 + (rb + w * 16) * 64;
        int kb = jt << 6;
#pragma unroll
        for (int i = 0; i < 2; i++) {
            int rl = rb + w * 16 + i * 8 + l3;
            gload16(Bt + (size_t)(o0 + rl) * ldb + kb + qq * 8, dst + i * 512);
        }
    };
    auto stgA = [&](int h, int sp0, int sp1) {
        if (h >= 4 * NKT) return;
        int jt = h >> 2;
        int rb = (h & 2) ? 128 : 0;
        unsigned short* dst = As + (jt & 1) * 16384 + (rb + w * 16) * 64;
#pragma unroll
        for (int i = 0; i < 2; i++) {
            const unsigned short* g;
            if (TAPS) {
                int sp = i ? sp1 : sp0;
                g = (sp >= 0) ? (A + (size_t)sp * lda + (jt & 7) * 64 + qq * 8) : zp;
            } else {
                int rl = rb + w * 16 + i * 8 + l3;
                g = A + (size_t)(p0 + rl) * lda + (jt << 6) + qq * 8;
            }
            gload16(g, dst + i * 512);
        }
    };
    auto ldsp = [&](int h, int& sp0, int& sp1) {   // prefetch gather rows for A-stream h
        if (TAPS && h < 4 * NKT) {
            int jt = h >> 2, tap = jt >> 3;
            int rb = (h & 2) ? 128 : 0;
            int rl = rb + w * 16 + l3;
            sp0 = srcp_s[rl * TAPS + tap];
            sp1 = srcp_s[(rl + 8) * TAPS + tap];
        }
    };

    // prologue
    if (TAPS) {
        for (int idx = t; idx < 256 * TAPS; idx += 512)
            srcp_s[idx] = srcp[(size_t)p0 * TAPS + idx];
    }
    __syncthreads();
    int sp0 = -1, sp1 = -1;
    ldsp(0, sp0, sp1); stgA(0, sp0, sp1);
    stgB(1);
    ldsp(2, sp0, sp1); stgA(2, sp0, sp1);
    stgB(3);
    ldsp(4, sp0, sp1); stgA(4, sp0, sp1);
    stgB(5);
    ldsp(6, sp0, sp1);                     // sp for tile0 ph1's stgA(6)
    WAITV(4);                              // streams 0..3 landed
    barrier_sync();

#define RD_A(MIH) do {                                                          \
    _Pragma("unroll")                                                           \
    for (int kk = 0; kk < 2; kk++) {                                            \
        int sa = ((kk * 4 + qh) ^ x7) * 8;                                      \
        _Pragma("unroll")                                                       \
        for (int m = 0; m < 4; m++)                                             \
            af[m][kk] = *(const short8*)&as_[((((MIH)*4+m)*2 + wr)*16 + lm)*64 + sa]; \
    } } while (0)
#define RD_B(NJH, BF) do {                                                      \
    _Pragma("unroll")                                                           \
    for (int kk = 0; kk < 2; kk++) {                                            \
        int sa = ((kk * 4 + qh) ^ x7) * 8;                                      \
        _Pragma("unroll")                                                       \
        for (int n = 0; n < 2; n++)                                             \
            BF[n][kk] = *(const short8*)&bs_[((((NJH)*2+n)*4 + wc)*16 + lm)*64 + sa]; \
    } } while (0)
#define MFMA_Q(MIH, NJH, BF)                                                    \
    __builtin_amdgcn_s_setprio(1);                                              \
    _Pragma("unroll")                                                           \
    for (int kk = 0; kk < 2; kk++)                                              \
        _Pragma("unroll")                                                       \
        for (int m = 0; m < 4; m++)                                             \
            _Pragma("unroll")                                                   \
            for (int n = 0; n < 2; n++)                                         \
                acc[(MIH)*4+m][(NJH)*2+n] = __builtin_amdgcn_mfma_f32_16x16x32_bf16( \
                    af[m][kk], BF[n][kk], acc[(MIH)*4+m][(NJH)*2+n], 0, 0, 0);  \
    __builtin_amdgcn_s_setprio(0)

    short8 af[4][2], bf0[2][2], bf1[2][2];
#pragma unroll 1
    for (int kt = 0; kt < NKT; ++kt) {
        const unsigned short* as_ = As + (kt & 1) * 16384;
        const unsigned short* bs_ = Bs + (kt & 1) * 16384;
        const bool last = (kt == NKT - 1);
        // ---- ph1 (0,0): stage A1(kt+1) | read A0+B0 | mfma | drain | bar
        if (!last) stgA(4 * kt + 6, sp0, sp1);
        RD_A(0); RD_B(0, bf0);
        MFMA_Q(0, 0, bf0);
        if (!last) ldsp(4 * kt + 8, sp0, sp1);   // sp for ph3's stgA
        WAITL0();
        barrier_sync();
        // ---- ph2 (0,1): stage B1(kt+1) | read B1 | mfma | drain | bar
        if (!last) stgB(4 * kt + 7);
        RD_B(1, bf1);
        MFMA_Q(0, 1, bf1);
        WAITL0();
        barrier_sync();
        // ---- ph3 (1,0): stage A0(kt+2) | read A1 | mfma | drain | bar
        if (!last) stgA(4 * kt + 8, sp0, sp1);
        RD_A(1);
        MFMA_Q(1, 0, bf0);
        if (!last) ldsp(4 * kt + 10, sp0, sp1);  // sp for next tile ph1's stgA
        WAITL0();
        barrier_sync();
        // ---- ph4 (1,1): stage B0(kt+2) | mfma | counted vmcnt | bar
        if (!last) stgB(4 * kt + 9);
        MFMA_Q(1, 1, bf1);
        WAITL0();
        if (kt == NKT - 2) { WAITV(0); } else if (!last) { WAITV(4); }
        barrier_sync();
    }
#undef RD_A
#undef RD_B
#undef MFMA_Q

    // epilogue: C/D layout col=lane&15, row=(lane>>4)*4+reg  [m89-verified]
#pragma unroll
    for (int mi = 0; mi < 8; mi++) {
#pragma unroll
        for (int nj = 0; nj < 4; nj++) {
            int col = o0 + (nj * 4 + wc) * 16 + lm;
#pragma unroll
            for (int r = 0; r < 4; r++) {
                int row = p0 + (mi * 2 + wr) * 16 + qh * 4 + r;
                float v = acc[mi][nj][r];
                size_t idx = (size_t)row * ldc + col;
                if (EPI == 0) {
                    ((unsigned short*)Yv)[idx] = f2bf(v + bias[col]);
                } else if (EPI == 1) {
                    ((unsigned short*)Yv)[idx] = f2bf(gelu_fast(v + bias[col]));
                } else if (EPI == 2) {
                    ((float*)Yv)[idx] = v + bias[col];
                } else {
                    ((float*)Yv)[idx] += v;
                }
            }
        }
    }
}

// ---------------------------------------------------------------------------
// LN1: out_bf16 = LN(x_f32 + conv_bf16)
__global__ __launch_bounds__(256) void ln1_kernel(const float* __restrict__ x,
                                                  const unsigned short* __restrict__ conv,
                                                  const float* __restrict__ g,
                                                  const float* __restrict__ beta,
                                                  unsigned short* __restrict__ h) {
    int p = blockIdx.x, t = threadIdx.x;
    size_t base = (size_t)p * DD;
    float v0 = x[base + t] + bf2f(conv[base + t]);
    float v1 = x[base + 256 + t] + bf2f(conv[base + 256 + t]);
    float s = v0 + v1, sq = v0 * v0 + v1 * v1;
#pragma unroll
    for (int off = 32; off > 0; off >>= 1) { s += __shfl_xor(s, off); sq += __shfl_xor(sq, off); }
    __shared__ float red[2][4];
    int wid = t >> 6, lane = t & 63;
    if (lane == 0) { red[0][wid] = s; red[1][wid] = sq; }
    __syncthreads();
    float S = red[0][0] + red[0][1] + red[0][2] + red[0][3];
    float SQ = red[1][0] + red[1][1] + red[1][2] + red[1][3];
    float mu = S * (1.f / DD);
    float var = SQ * (1.f / DD) - mu * mu;
    float rs = rsqrtf(var + 1e-5f);
    h[base + t]       = f2bf((v0 - mu) * rs * g[t] + beta[t]);
    h[base + 256 + t] = f2bf((v1 - mu) * rs * g[256 + t] + beta[256 + t]);
}

// LN2: out_f32 = LN(h_bf16 + out_f32) in place
__global__ __launch_bounds__(256) void ln2_kernel(const unsigned short* __restrict__ h,
                                                  float* __restrict__ out,
                                                  const float* __restrict__ g,
                                                  const float* __restrict__ beta) {
    int p = blockIdx.x, t = threadIdx.x;
    size_t base = (size_t)p * DD;
    float v0 = bf2f(h[base + t]) + out[base + t];
    float v1 = bf2f(h[base + 256 + t]) + out[base + 256 + t];
    float s = v0 + v1, sq = v0 * v0 + v1 * v1;
#pragma unroll
    for (int off = 32; off > 0; off >>= 1) { s += __shfl_xor(s, off); sq += __shfl_xor(sq, off); }
    __shared__ float red[2][4];
    int wid = t >> 6, lane = t & 63;
    if (lane == 0) { red[0][wid] = s; red[1][wid] = sq; }
    __syncthreads();
    float S = red[0][0] + red[0][1] + red[0][2] + red[0][3];
    float SQ = red[1][0] + red[1][1] + red[1][2] + red[1][3];
    float mu = S * (1.f / DD);
    float var = SQ * (1.f / DD) - mu * mu;
    float rs = rsqrtf(var + 1e-5f);
    out[base + t]       = (v0 - mu) * rs * g[t] + beta[t];
    out[base + 256 + t] = (v1 - mu) * rs * g[256 + t] + beta[256 + t];
}

// ---------------------------------------------------------------------------
extern "C" void kernel_launch(void* const* d_in, const int* in_sizes, int n_in,
                              void* d_out, int out_size, void* d_ws, size_t ws_size,
                              hipStream_t stream) {
    const float* x     = (const float*)d_in[0];
    const int*   chain = (const int*)d_in[1];
    const float* W3    = (const float*)d_in[2];
    const float* b3    = (const float*)d_in[3];
    const float* W5    = (const float*)d_in[4];
    const float* b5    = (const float*)d_in[5];
    const float* W7    = (const float*)d_in[6];
    const float* b7    = (const float*)d_in[7];
    const float* w1    = (const float*)d_in[8];
    const float* bm1   = (const float*)d_in[9];
    const float* w2    = (const float*)d_in[10];
    const float* bm2   = (const float*)d_in[11];
    const float* g1    = (const float*)d_in[12];
    const float* be1   = (const float*)d_in[13];
    const float* g2    = (const float*)d_in[14];
    const float* be2   = (const float*)d_in[15];
    float* out = (float*)d_out;

    const size_t ACT = (size_t)PTOT * DD * 2;     // 32 MB bf16 activation buffer
    char* ws = (char*)d_ws;
    size_t off = 0;
    unsigned short* Xb   = (unsigned short*)(ws + off); off += ACT;
    unsigned short* buf1 = (unsigned short*)(ws + off); off += ACT;
    unsigned short* buf2 = (unsigned short*)(ws + off); off += ACT;
    unsigned short* w3t  = (unsigned short*)(ws + off); off += (size_t)3 * DD * DD * 2;
    unsigned short* w5t  = (unsigned short*)(ws + off); off += (size_t)5 * DD * DD * 2;
    unsigned short* w7t  = (unsigned short*)(ws + off); off += (size_t)7 * DD * DD * 2;
    unsigned short* w1t  = (unsigned short*)(ws + off); off += (size_t)DD * HID * 2;
    unsigned short* w2t  = (unsigned short*)(ws + off); off += (size_t)DD * HID * 2;
    int* srcp3 = (int*)(ws + off); off += (size_t)PTOT * 3 * 4;
    int* srcp5 = (int*)(ws + off); off += (size_t)PTOT * 5 * 4;
    int* srcp7 = (int*)(ws + off); off += (size_t)PTOT * 7 * 4;
    unsigned short* zp = (unsigned short*)(ws + off); off += 256;
    size_t base_off = off;
    bool full = (ws_size >= base_off + (size_t)PTOT * HID * 2);
    unsigned short* Hb = (unsigned short*)(ws + base_off);  // 32MB chunked / 128MB full

    // prep
    convert_x<<<PTOT * DD / (256 * 4), 256, 0, stream>>>(x, Xb, zp);
    trans_wconv<<<(DD * DD * 3 + 255) / 256, 256, 0, stream>>>(W3, w3t, 3);
    trans_wconv<<<(DD * DD * 5 + 255) / 256, 256, 0, stream>>>(W5, w5t, 5);
    trans_wconv<<<(DD * DD * 7 + 255) / 256, 256, 0, stream>>>(W7, w7t, 7);
    trans_w1<<<DD * HID / 256, 256, 0, stream>>>(w1, w1t);
    trans_w2<<<DD * HID / 256, 256, 0, stream>>>(w2, w2t);
    make_srcp<<<(PTOT * 3 + 255) / 256, 256, 0, stream>>>(chain, srcp3, 3);
    make_srcp<<<(PTOT * 5 + 255) / 256, 256, 0, stream>>>(chain, srcp5, 5);
    make_srcp<<<(PTOT * 7 + 255) / 256, 256, 0, stream>>>(chain, srcp7, 7);

    dim3 gconv(PTOT / 256, DD / 256);   // 128 x 2 = 256 blocks (1/CU)

    mfma_gemm5<3, 0><<<gconv, 512, 0, stream>>>(Xb, DD, srcp3, w3t, 3 * DD, b3, buf1, DD, DD, zp);
    mfma_gemm5<5, 0><<<gconv, 512, 0, stream>>>(buf1, DD, srcp5, w5t, 5 * DD, b5, buf2, DD, DD, zp);
    mfma_gemm5<7, 0><<<gconv, 512, 0, stream>>>(buf2, DD, srcp7, w7t, 7 * DD, b7, buf1, DD, DD, zp);

    ln1_kernel<<<PTOT, 256, 0, stream>>>(x, buf1, g1, be1, buf2);

    if (full) {
        dim3 g1d(PTOT / 256, HID / 256);   // 128 x 8
        mfma_gemm5<0, 1><<<g1d, 512, 0, stream>>>(buf2, DD, nullptr, w1t, DD, bm1,
                                                  Hb, HID, DD, zp);
        mfma_gemm5<0, 2><<<gconv, 512, 0, stream>>>(Hb, HID, nullptr, w2t, HID, bm2,
                                                    out, DD, HID, zp);
    } else {
        for (int jc = 0; jc < 4; jc++) {
            mfma_gemm5<0, 1><<<gconv, 512, 0, stream>>>(buf2, DD, nullptr,
                                                        w1t + (size_t)jc * DD * DD, DD,
                                                        bm1 + jc * DD, Hb, DD, DD, zp);
            if (jc == 0)
                mfma_gemm5<0, 2><<<gconv, 512, 0, stream>>>(Hb, DD, nullptr,
                                                            w2t + jc * DD, HID, bm2,
                                                            out, DD, DD, zp);
            else
                mfma_gemm5<0, 3><<<gconv, 512, 0, stream>>>(Hb, DD, nullptr,
                                                            w2t + jc * DD, HID, bm2,
                                                            out, DD, DD, zp);
        }
    }

    ln2_kernel<<<PTOT, 256, 0, stream>>>(buf2, out, g2, be2);
}

// Round 7
// 652.688 us; speedup vs baseline: 1.1414x; 1.1414x over previous
//
#include <hip/hip_runtime.h>
#include <math.h>

#define BB 8
#define LL 4096
#define DD 512
#define PTOT (BB*LL)      // 32768 positions
#define HID  2048

typedef __attribute__((ext_vector_type(8))) short short8;   // 8 bf16 (4 VGPRs)
typedef __attribute__((ext_vector_type(4))) float f32x4;

typedef __attribute__((address_space(1))) const unsigned int gconst_u32;
typedef __attribute__((address_space(3))) unsigned int lds_u32;

__device__ __forceinline__ void gload16(const void* g, void* l) {
    // async global->LDS DMA, 16B per lane; LDS dest = wave-uniform base + lane*16
    __builtin_amdgcn_global_load_lds((gconst_u32*)g, (lds_u32*)l, 16, 0, 0);
}

__device__ __forceinline__ unsigned short f2bf(float f) {
    union { float f; unsigned int u; } v; v.f = f;
    unsigned int r = v.u + 0x7fffu + ((v.u >> 16) & 1u);
    return (unsigned short)(r >> 16);
}
__device__ __forceinline__ float bf2f(unsigned short h) {
    union { unsigned int u; float f; } v; v.u = ((unsigned int)h) << 16;
    return v.f;
}
__device__ __forceinline__ float gelu_fast(float x) {
    float x2 = x * x;
    float t  = x * fmaf(0.044715f, x2, 1.0f);
    float e  = __builtin_amdgcn_exp2f(-2.3021143f * t);   // e^{-2z}
    return x * __builtin_amdgcn_rcpf(1.0f + e);
}

__device__ __forceinline__ void barrier_sync() {
    asm volatile("" ::: "memory");
    __builtin_amdgcn_s_barrier();
    asm volatile("" ::: "memory");
}
#define WAITV(N) asm volatile("s_waitcnt vmcnt(" #N ")" ::: "memory")
#define WAITL0() asm volatile("s_waitcnt lgkmcnt(0)" ::: "memory")
#define SCHED0() __builtin_amdgcn_sched_barrier(0)

// ---------------------------------------------------------------------------
// x fp32 -> bf16; also zero the 256B zero-page (ws is re-poisoned each launch)
__global__ __launch_bounds__(256) void convert_x(const float* __restrict__ x,
                                                 unsigned short* __restrict__ xb,
                                                 unsigned short* __restrict__ zp) {
    int tid = blockIdx.x * 256 + threadIdx.x;
    if (blockIdx.x == 0 && threadIdx.x < 128) zp[threadIdx.x] = 0;
    float4 v = ((const float4*)x)[tid];
    uint2 o;
    o.x = (unsigned int)f2bf(v.x) | ((unsigned int)f2bf(v.y) << 16);
    o.y = (unsigned int)f2bf(v.z) | ((unsigned int)f2bf(v.w) << 16);
    ((uint2*)xb)[tid] = o;
}

// conv W (o,c,k) -> Wt[o][k*512+c] bf16
__global__ __launch_bounds__(256) void trans_wconv(const float* __restrict__ W,
                                                   unsigned short* __restrict__ Wt, int K) {
    int tid = blockIdx.x * 256 + threadIdx.x;
    if (tid >= DD * DD * K) return;
    int o  = tid / (K * DD);
    int kc = tid - o * K * DD;
    int k  = kc >> 9;
    int c  = kc & (DD - 1);
    Wt[tid] = f2bf(W[(o * DD + c) * K + k]);
}

// mlp_w1 (c, n) -> W1t[n][c]
__global__ __launch_bounds__(256) void trans_w1(const float* __restrict__ W,
                                                unsigned short* __restrict__ Wt) {
    int tid = blockIdx.x * 256 + threadIdx.x;   // n*512 + c
    int n = tid >> 9;
    int c = tid & (DD - 1);
    Wt[tid] = f2bf(W[c * HID + n]);
}

// mlp_w2 (h, n) -> W2t[n][h]
__global__ __launch_bounds__(256) void trans_w2(const float* __restrict__ W,
                                                unsigned short* __restrict__ Wt) {
    int tid = blockIdx.x * 256 + threadIdx.x;   // n*2048 + h
    int n = tid >> 11;
    int h = tid & (HID - 1);
    Wt[tid] = f2bf(W[h * DD + n]);
}

// srcp[p*K + k] = p + k - pad if in-range and chain matches, else -1
__global__ __launch_bounds__(256) void make_srcp(const int* __restrict__ chain,
                                                 int* __restrict__ srcp, int K) {
    int tid = blockIdx.x * 256 + threadIdx.x;
    if (tid >= PTOT * K) return;
    int p = tid / K;
    int k = tid - p * K;
    int b = p >> 12;
    int l = p & (LL - 1);
    int pad = (K - 1) >> 1;
    int l2 = l + k - pad;
    bool ok = (l2 >= 0) && (l2 < LL) && (chain[b * LL + l2] == chain[b * LL + l]);
    srcp[tid] = ok ? (p + k - pad) : -1;
}

// ---------------------------------------------------------------------------
// 256x256 MFMA GEMM, 2 super-phases per K-tile (round 7).
// 512 threads = 8 waves (2M x 4N), wave tile 128x64, BK=64, dbuf LDS 128KB.
// vs round 5 (4 phases, 668us): merge to 2 phases/tile, halving barriers and
// lgkm drains. Phase discipline is EXACTLY round 5's (proven): RD -> STG ->
// lgkmcnt(0) -> sched_barrier(0) -> setprio-MFMA -> barrier. RD MUST precede
// STG: gload16 is an LDS-writing intrinsic and the compiler cannot prove its
// dest is disjoint from the ds_read addrs, so STG-first forces conservative
// vmcnt ordering in the phase interior (round-6 regression, 745us).
//   P1: read A0(8)+B0(4)+B1(4) | stage A1(kt+1),B1(kt+1) | MFMA (0,0),(0,1)
//   P2: read A1(8)             | stage A0(kt+2),B0(kt+2) | MFMA (1,0),(1,1)
// Overwrite safety (reader's lgkmcnt(0) precedes its barrier; DMA issuer has
// passed that barrier): A1 slot: rd P2(kt) -> iss P1(kt+1) = +1 bar; B1: rd
// P1(kt) -> iss P1(kt+1) = +2; A0: rd P1(kt) -> iss P2(kt) = +1; B0: same +1.
// Counted vmcnt: WAITV(4) at end-P2(kt) leaves exactly streams A0,B0(kt+2)
// in flight => streams <=4kt+7 landed = tile kt+1's full needs (A0,B0,A1,B1).
// WAITV(0) at kt=NKT-2 (its P2 stages clip on h>=4NKT). Last tile: no stage.
// Conv gather: sp regs pipelined (ldsp after MFMA cluster, used next phase).
// EPI: 0 bf16=acc+bias; 1 bf16=gelu(acc+bias); 2 f32=acc+bias; 3 f32+=acc.
template <int TAPS, int EPI>
__global__ __launch_bounds__(512) void mfma_gemm6(
        const unsigned short* __restrict__ A, int lda,
        const int* __restrict__ srcp,
        const unsigned short* __restrict__ Bt, int ldb,
        const float* __restrict__ bias,
        void* __restrict__ Yv, int ldc, int Kspan,
        const unsigned short* __restrict__ zp) {
    __shared__ alignas(16) unsigned short As[2 * 256 * 64];   // 64 KB
    __shared__ alignas(16) unsigned short Bs[2 * 256 * 64];   // 64 KB
    __shared__ int srcp_s[TAPS > 0 ? 256 * TAPS : 4];         // <=7 KB

    const int t = threadIdx.x;
    const int lane = t & 63, w = t >> 6;
    const int wr = w & 1, wc = w >> 1;          // 2M x 4N waves
    const int lm = lane & 15, qh = lane >> 4, x7 = lane & 7;
    const int qq = (lane & 7) ^ (lane >> 3);    // staged source quad (swizzle)
    const int l3 = lane >> 3;                   // row-within-8
    const int p0 = blockIdx.x * 256;
    const int o0 = blockIdx.y * 256;
    const int NKT = TAPS ? TAPS * 8 : (Kspan >> 6);

    f32x4 acc[8][4];
#pragma unroll
    for (int mi = 0; mi < 8; mi++)
#pragma unroll
        for (int nj = 0; nj < 4; nj++) acc[mi][nj] = (f32x4){0.f, 0.f, 0.f, 0.f};

    // stream h: tile jt=h>>2 (buffer jt&1); h&1: 0=A,1=B; h&2: row half
    auto stgB = [&](int h) {
        if (h >= 4 * NKT) return;
        int jt = h >> 2;
        int rb = (h & 2) ? 128 : 0;
        unsigned short* dst = Bs + (jt & 1) * 16384 + (rb + w * 16) * 64;
        int kb = jt << 6;
#pragma unroll
        for (int i = 0; i < 2; i++) {
            int rl = rb + w * 16 + i * 8 + l3;
            gload16(Bt + (size_t)(o0 + rl) * ldb + kb + qq * 8, dst + i * 512);
        }
    };
    auto stgA = [&](int h, int sp0, int sp1) {
        if (h >= 4 * NKT) return;
        int jt = h >> 2;
        int rb = (h & 2) ? 128 : 0;
        unsigned short* dst = As + (jt & 1) * 16384 + (rb + w * 16) * 64;
#pragma unroll
        for (int i = 0; i < 2; i++) {
            const unsigned short* g;
            if (TAPS) {
                int sp = i ? sp1 : sp0;
                g = (sp >= 0) ? (A + (size_t)sp * lda + (jt & 7) * 64 + qq * 8) : zp;
            } else {
                int rl = rb + w * 16 + i * 8 + l3;
                g = A + (size_t)(p0 + rl) * lda + (jt << 6) + qq * 8;
            }
            gload16(g, dst + i * 512);
        }
    };
    auto ldsp = [&](int h, int& sp0, int& sp1) {   // prefetch gather rows for A-stream h
        if (TAPS && h < 4 * NKT) {
            int jt = h >> 2, tap = jt >> 3;
            int rb = (h & 2) ? 128 : 0;
            int rl = rb + w * 16 + l3;
            sp0 = srcp_s[rl * TAPS + tap];
            sp1 = srcp_s[(rl + 8) * TAPS + tap];
        }
    };

    // prologue
    if (TAPS) {
        for (int idx = t; idx < 256 * TAPS; idx += 512)
            srcp_s[idx] = srcp[(size_t)p0 * TAPS + idx];
    }
    __syncthreads();
    int sp0 = -1, sp1 = -1;
    ldsp(0, sp0, sp1); stgA(0, sp0, sp1);
    stgB(1);
    ldsp(2, sp0, sp1); stgA(2, sp0, sp1);
    stgB(3);
    ldsp(4, sp0, sp1); stgA(4, sp0, sp1);
    stgB(5);
    ldsp(6, sp0, sp1);                     // sp for tile0 P1's stgA(6)
    WAITV(4);                              // streams 0..3 (tile0) landed
    barrier_sync();

#define RD_A(MIH) do {                                                          \
    _Pragma("unroll")                                                           \
    for (int kk = 0; kk < 2; kk++) {                                            \
        int sa = ((kk * 4 + qh) ^ x7) * 8;                                      \
        _Pragma("unroll")                                                       \
        for (int m = 0; m < 4; m++)                                             \
            af[m][kk] = *(const short8*)&as_[((((MIH)*4+m)*2 + wr)*16 + lm)*64 + sa]; \
    } } while (0)
#define RD_B(NJH, BF) do {                                                      \
    _Pragma("unroll")                                                           \
    for (int kk = 0; kk < 2; kk++) {                                            \
        int sa = ((kk * 4 + qh) ^ x7) * 8;                                      \
        _Pragma("unroll")                                                       \
        for (int n = 0; n < 2; n++)                                             \
            BF[n][kk] = *(const short8*)&bs_[((((NJH)*2+n)*4 + wc)*16 + lm)*64 + sa]; \
    } } while (0)
#define MFMA_Q(MIH, NJH, BF)                                                    \
    __builtin_amdgcn_s_setprio(1);                                              \
    _Pragma("unroll")                                                           \
    for (int kk = 0; kk < 2; kk++)                                              \
        _Pragma("unroll")                                                       \
        for (int m = 0; m < 4; m++)                                             \
            _Pragma("unroll")                                                   \
            for (int n = 0; n < 2; n++)                                         \
                acc[(MIH)*4+m][(NJH)*2+n] = __builtin_amdgcn_mfma_f32_16x16x32_bf16( \
                    af[m][kk], BF[n][kk], acc[(MIH)*4+m][(NJH)*2+n], 0, 0, 0);  \
    __builtin_amdgcn_s_setprio(0)

    short8 af[4][2], bf0[2][2], bf1[2][2];
#pragma unroll 1
    for (int kt = 0; kt < NKT; ++kt) {
        const unsigned short* as_ = As + (kt & 1) * 16384;
        const unsigned short* bs_ = Bs + (kt & 1) * 16384;
        const bool last = (kt == NKT - 1);
        // ---- P1: read A0+B0+B1 | stage A1(kt+1),B1(kt+1) | mfma (0,0),(0,1)
        RD_A(0); RD_B(0, bf0); RD_B(1, bf1);
        if (!last) { stgA(4 * kt + 6, sp0, sp1); stgB(4 * kt + 7); }
        WAITL0(); SCHED0();
        MFMA_Q(0, 0, bf0);
        MFMA_Q(0, 1, bf1);
        if (!last) ldsp(4 * kt + 8, sp0, sp1);   // sp for P2's stgA
        barrier_sync();
        // ---- P2: read A1 | stage A0(kt+2),B0(kt+2) | mfma (1,0),(1,1) | vmcnt
        RD_A(1);
        if (!last) { stgA(4 * kt + 8, sp0, sp1); stgB(4 * kt + 9); }
        WAITL0(); SCHED0();
        MFMA_Q(1, 0, bf0);
        MFMA_Q(1, 1, bf1);
        if (!last) ldsp(4 * kt + 10, sp0, sp1);  // sp for next P1's stgA
        if (kt == NKT - 2) { WAITV(0); } else if (!last) { WAITV(4); }
        barrier_sync();
    }
#undef RD_A
#undef RD_B
#undef MFMA_Q

    // epilogue: C/D layout col=lane&15, row=(lane>>4)*4+reg  [m89-verified]
#pragma unroll
    for (int mi = 0; mi < 8; mi++) {
#pragma unroll
        for (int nj = 0; nj < 4; nj++) {
            int col = o0 + (nj * 4 + wc) * 16 + lm;
#pragma unroll
            for (int r = 0; r < 4; r++) {
                int row = p0 + (mi * 2 + wr) * 16 + qh * 4 + r;
                float v = acc[mi][nj][r];
                size_t idx = (size_t)row * ldc + col;
                if (EPI == 0) {
                    ((unsigned short*)Yv)[idx] = f2bf(v + bias[col]);
                } else if (EPI == 1) {
                    ((unsigned short*)Yv)[idx] = f2bf(gelu_fast(v + bias[col]));
                } else if (EPI == 2) {
                    ((float*)Yv)[idx] = v + bias[col];
                } else {
                    ((float*)Yv)[idx] += v;
                }
            }
        }
    }
}

// ---------------------------------------------------------------------------
// LN1: out_bf16 = LN(x_f32 + conv_bf16)
__global__ __launch_bounds__(256) void ln1_kernel(const float* __restrict__ x,
                                                  const unsigned short* __restrict__ conv,
                                                  const float* __restrict__ g,
                                                  const float* __restrict__ beta,
                                                  unsigned short* __restrict__ h) {
    int p = blockIdx.x, t = threadIdx.x;
    size_t base = (size_t)p * DD;
    float v0 = x[base + t] + bf2f(conv[base + t]);
    float v1 = x[base + 256 + t] + bf2f(conv[base + 256 + t]);
    float s = v0 + v1, sq = v0 * v0 + v1 * v1;
#pragma unroll
    for (int off = 32; off > 0; off >>= 1) { s += __shfl_xor(s, off); sq += __shfl_xor(sq, off); }
    __shared__ float red[2][4];
    int wid = t >> 6, lane = t & 63;
    if (lane == 0) { red[0][wid] = s; red[1][wid] = sq; }
    __syncthreads();
    float S = red[0][0] + red[0][1] + red[0][2] + red[0][3];
    float SQ = red[1][0] + red[1][1] + red[1][2] + red[1][3];
    float mu = S * (1.f / DD);
    float var = SQ * (1.f / DD) - mu * mu;
    float rs = rsqrtf(var + 1e-5f);
    h[base + t]       = f2bf((v0 - mu) * rs * g[t] + beta[t]);
    h[base + 256 + t] = f2bf((v1 - mu) * rs * g[256 + t] + beta[256 + t]);
}

// LN2: out_f32 = LN(h_bf16 + out_f32) in place
__global__ __launch_bounds__(256) void ln2_kernel(const unsigned short* __restrict__ h,
                                                  float* __restrict__ out,
                                                  const float* __restrict__ g,
                                                  const float* __restrict__ beta) {
    int p = blockIdx.x, t = threadIdx.x;
    size_t base = (size_t)p * DD;
    float v0 = bf2f(h[base + t]) + out[base + t];
    float v1 = bf2f(h[base + 256 + t]) + out[base + 256 + t];
    float s = v0 + v1, sq = v0 * v0 + v1 * v1;
#pragma unroll
    for (int off = 32; off > 0; off >>= 1) { s += __shfl_xor(s, off); sq += __shfl_xor(sq, off); }
    __shared__ float red[2][4];
    int wid = t >> 6, lane = t & 63;
    if (lane == 0) { red[0][wid] = s; red[1][wid] = sq; }
    __syncthreads();
    float S = red[0][0] + red[0][1] + red[0][2] + red[0][3];
    float SQ = red[1][0] + red[1][1] + red[1][2] + red[1][3];
    float mu = S * (1.f / DD);
    float var = SQ * (1.f / DD) - mu * mu;
    float rs = rsqrtf(var + 1e-5f);
    out[base + t]       = (v0 - mu) * rs * g[t] + beta[t];
    out[base + 256 + t] = (v1 - mu) * rs * g[256 + t] + beta[256 + t];
}

// ---------------------------------------------------------------------------
extern "C" void kernel_launch(void* const* d_in, const int* in_sizes, int n_in,
                              void* d_out, int out_size, void* d_ws, size_t ws_size,
                              hipStream_t stream) {
    const float* x     = (const float*)d_in[0];
    const int*   chain = (const int*)d_in[1];
    const float* W3    = (const float*)d_in[2];
    const float* b3    = (const float*)d_in[3];
    const float* W5    = (const float*)d_in[4];
    const float* b5    = (const float*)d_in[5];
    const float* W7    = (const float*)d_in[6];
    const float* b7    = (const float*)d_in[7];
    const float* w1    = (const float*)d_in[8];
    const float* bm1   = (const float*)d_in[9];
    const float* w2    = (const float*)d_in[10];
    const float* bm2   = (const float*)d_in[11];
    const float* g1    = (const float*)d_in[12];
    const float* be1   = (const float*)d_in[13];
    const float* g2    = (const float*)d_in[14];
    const float* be2   = (const float*)d_in[15];
    float* out = (float*)d_out;

    const size_t ACT = (size_t)PTOT * DD * 2;     // 32 MB bf16 activation buffer
    char* ws = (char*)d_ws;
    size_t off = 0;
    unsigned short* Xb   = (unsigned short*)(ws + off); off += ACT;
    unsigned short* buf1 = (unsigned short*)(ws + off); off += ACT;
    unsigned short* buf2 = (unsigned short*)(ws + off); off += ACT;
    unsigned short* w3t  = (unsigned short*)(ws + off); off += (size_t)3 * DD * DD * 2;
    unsigned short* w5t  = (unsigned short*)(ws + off); off += (size_t)5 * DD * DD * 2;
    unsigned short* w7t  = (unsigned short*)(ws + off); off += (size_t)7 * DD * DD * 2;
    unsigned short* w1t  = (unsigned short*)(ws + off); off += (size_t)DD * HID * 2;
    unsigned short* w2t  = (unsigned short*)(ws + off); off += (size_t)DD * HID * 2;
    int* srcp3 = (int*)(ws + off); off += (size_t)PTOT * 3 * 4;
    int* srcp5 = (int*)(ws + off); off += (size_t)PTOT * 5 * 4;
    int* srcp7 = (int*)(ws + off); off += (size_t)PTOT * 7 * 4;
    unsigned short* zp = (unsigned short*)(ws + off); off += 256;
    size_t base_off = off;
    bool full = (ws_size >= base_off + (size_t)PTOT * HID * 2);
    unsigned short* Hb = (unsigned short*)(ws + base_off);  // 32MB chunked / 128MB full

    // prep
    convert_x<<<PTOT * DD / (256 * 4), 256, 0, stream>>>(x, Xb, zp);
    trans_wconv<<<(DD * DD * 3 + 255) / 256, 256, 0, stream>>>(W3, w3t, 3);
    trans_wconv<<<(DD * DD * 5 + 255) / 256, 256, 0, stream>>>(W5, w5t, 5);
    trans_wconv<<<(DD * DD * 7 + 255) / 256, 256, 0, stream>>>(W7, w7t, 7);
    trans_w1<<<DD * HID / 256, 256, 0, stream>>>(w1, w1t);
    trans_w2<<<DD * HID / 256, 256, 0, stream>>>(w2, w2t);
    make_srcp<<<(PTOT * 3 + 255) / 256, 256, 0, stream>>>(chain, srcp3, 3);
    make_srcp<<<(PTOT * 5 + 255) / 256, 256, 0, stream>>>(chain, srcp5, 5);
    make_srcp<<<(PTOT * 7 + 255) / 256, 256, 0, stream>>>(chain, srcp7, 7);

    dim3 gconv(PTOT / 256, DD / 256);   // 128 x 2 = 256 blocks (1/CU)

    mfma_gemm6<3, 0><<<gconv, 512, 0, stream>>>(Xb, DD, srcp3, w3t, 3 * DD, b3, buf1, DD, DD, zp);
    mfma_gemm6<5, 0><<<gconv, 512, 0, stream>>>(buf1, DD, srcp5, w5t, 5 * DD, b5, buf2, DD, DD, zp);
    mfma_gemm6<7, 0><<<gconv, 512, 0, stream>>>(buf2, DD, srcp7, w7t, 7 * DD, b7, buf1, DD, DD, zp);

    ln1_kernel<<<PTOT, 256, 0, stream>>>(x, buf1, g1, be1, buf2);

    if (full) {
        dim3 g1d(PTOT / 256, HID / 256);   // 128 x 8
        mfma_gemm6<0, 1><<<g1d, 512, 0, stream>>>(buf2, DD, nullptr, w1t, DD, bm1,
                                                  Hb, HID, DD, zp);
        mfma_gemm6<0, 2><<<gconv, 512, 0, stream>>>(Hb, HID, nullptr, w2t, HID, bm2,
                                                    out, DD, HID, zp);
    } else {
        for (int jc = 0; jc < 4; jc++) {
            mfma_gemm6<0, 1><<<gconv, 512, 0, stream>>>(buf2, DD, nullptr,
                                                        w1t + (size_t)jc * DD * DD, DD,
                                                        bm1 + jc * DD, Hb, DD, DD, zp);
            if (jc == 0)
                mfma_gemm6<0, 2><<<gconv, 512, 0, stream>>>(Hb, DD, nullptr,
                                                            w2t + jc * DD, HID, bm2,
                                                            out, DD, DD, zp);
            else
                mfma_gemm6<0, 3><<<gconv, 512, 0, stream>>>(Hb, DD, nullptr,
                                                            w2t + jc * DD, HID, bm2,
                                                            out, DD, DD, zp);
        }
    }

    ln2_kernel<<<PTOT, 256, 0, stream>>>(buf2, out, g2, be2);
}